// Round 14
// baseline (273.596 us; speedup 1.0000x reference)
//
#include <hip/hip_runtime.h>
#include <cstdint>
#include <cstddef>

// ---------------- problem constants ----------------
constexpr int kLq = 128;        // query length
constexpr int kLd = 512;        // doc length
constexpr int kD  = 64;         // embed dim
constexpr int kB  = 128;        // 1 pos + 127 neg docs
constexpr int kC1 = 8;          // conv1 channels
constexpr int kC2 = 16;         // conv2 channels
constexpr int kTileC = 51;      // output cols per tile
constexpr int kNTiles = 10;     // 10*51 = 510
constexpr int kMCols = 53;      // kTileC + 2 input cols needed
constexpr int kNCand = kNTiles * 8;  // 80 candidates per (c,r) row
constexpr int kNPair = kC1 * kTileC; // 408 (c,j) columns per tile

// LDS pitches (floats)
constexpr int QT_PITCH = 132;   // query_t[d][q]: 64 x 132
constexpr int DS_PITCH = 68;    // doc_s[l][d]:  56 x 68
constexpr int MS_PITCH = 57;    // m_s[q][l]:   128 x 57  (4*57 mod 32 = 4: no write conflicts)

// LDS layout (floats). q_t/d_s staging is dead after matmul; m_s overlays
// q_t, ps overlays d_s. halfkeys (u64) live in a dedicated region.
constexpr int kQtOff = 0;                      // 8448 floats
constexpr int kDsOff = 64 * QT_PITCH;          // 3808 floats -> end 12256
constexpr int kMsOff = 0;                      // 7296 floats (overlay q_t)
constexpr int kPsOff = kDsOff;                 // 8*8*52 = 3328 (overlay d_s)
constexpr int kHkOff = kDsOff + 56 * DS_PITCH; // 12256 (byte 49024, 8B-aligned)
constexpr int kLdsFloats = kHkOff + kNPair * 8 * 2;  // + 6528 = 18784 floats = 75,136 B

// ---------------------------------------------------------------------
// Packed-key top-K. Values are post-ReLU (>= 0, never -0.0), so IEEE bits
// are monotone as u32. key = (bits(v)<<32) | ~idx gives u64-descending ==
// (value desc, idx asc) — jax.lax.top_k's earliest-index-wins order.
// Keys are UNIQUE (distinct idx) -> strict-'>' carry-down is an exact
// sorted insert and is ORDER-INDEPENDENT (safe for merging lists).
// Verified on HW round 13 (absmax 0.0).
// ---------------------------------------------------------------------
__device__ __forceinline__ uint64_t pack_key(float v, unsigned idx) {
  return ((uint64_t)__float_as_uint(v) << 32) | (uint32_t)(~idx);
}

template <int K>
__device__ __forceinline__ void topk_u64(uint64_t (&key)[K], uint64_t c) {
#pragma unroll
  for (int k = 0; k < K; ++k) {
    const bool g = c > key[k];
    const uint64_t hi = g ? c : key[k];
    c = g ? key[k] : c;
    key[k] = hi;
  }
}

// =====================================================================
// Kernel A: per (doc, 51-col tile): m = q.docT -> conv1+relu ->
// top-8-of-126 rows per column (2 half-streams of 63 + exact u64 merge)
// -> per-tile top-8-of-51 cols -> candidate lists (idx-ascending slots).
// 1024 thr, 75.1 KB LDS -> 2 blocks/CU x 16 waves = 32 waves/CU (max).
// =====================================================================
__global__ __launch_bounds__(1024, 8)
void convpool1_kernel(const float* __restrict__ query,
                      const float* __restrict__ pos_doc,
                      const float* __restrict__ neg_docs,
                      const float* __restrict__ c1w,
                      const float* __restrict__ c1b,
                      float* __restrict__ candv,
                      int* __restrict__ candi) {
  __shared__ float lds[kLdsFloats];
  float* q_t = lds + kQtOff;          // [64][132] transposed [d][q]
  float* d_s = lds + kDsOff;          // [56][68]  [l_local][d]
  float* m_s = lds + kMsOff;          // [128][57] (overlays q_t after matmul)
  float* ps  = lds + kPsOff;          // [8][8][52] (overlays d_s)
  uint64_t* hk = reinterpret_cast<uint64_t*>(lds + kHkOff);  // [408][8]

  const int tid  = threadIdx.x;
  const int tile = blockIdx.x;
  const int b    = blockIdx.y;
  const int l0g  = tile * kTileC;

  const float* doc =
      (b == 0) ? pos_doc : (neg_docs + (size_t)(b - 1) * kLd * kD);

  // ---- load query transposed (lanes write consecutive q -> consecutive
  // banks, conflict-free); 2048 float4 over 1024 threads = 2 iters ----
  {
    const float4* qf4 = reinterpret_cast<const float4*>(query);
    for (int e = tid; e < (kLq * kD) / 4; e += 1024) {
      const int q  = e & 127;
      const int f4 = e >> 7;            // 0..15
      const float4 v = qf4[q * 16 + f4];
      const int d0 = f4 << 2;
      q_t[(d0 + 0) * QT_PITCH + q] = v.x;
      q_t[(d0 + 1) * QT_PITCH + q] = v.y;
      q_t[(d0 + 2) * QT_PITCH + q] = v.z;
      q_t[(d0 + 3) * QT_PITCH + q] = v.w;
    }
  }
  // ---- load doc rows l0g..l0g+52; zero pad rows 53..55 (896 float4) ----
  if (tid < 56 * 16) {
    const int l  = tid >> 4;
    const int d0 = (tid & 15) << 2;
    float4 v = make_float4(0.f, 0.f, 0.f, 0.f);
    if (l < kMCols)
      v = reinterpret_cast<const float4*>(doc + (size_t)(l0g + l) * kD)[tid & 15];
    *reinterpret_cast<float4*>(&d_s[l * DS_PITCH + d0]) = v;
  }
  __syncthreads();

  // ---- m[q][l] = sum_d q[q][d]*doc[l][d]; 2q x 4l blocks, 896 threads ----
  float acc[2][4] = {};
  if (tid < 64 * 14) {
    const int q0 = (tid & 63) << 1;   // 0..126 step 2
    const int l0 = (tid >> 6) << 2;   // 0..52  step 4
#pragma unroll 4
    for (int d = 0; d < kD; d += 4) {
      float2 qv[4];
#pragma unroll
      for (int j = 0; j < 4; ++j)
        qv[j] = *reinterpret_cast<const float2*>(&q_t[(d + j) * QT_PITCH + q0]);
      float4 dv[4];
#pragma unroll
      for (int li = 0; li < 4; ++li)
        dv[li] = *reinterpret_cast<const float4*>(&d_s[(l0 + li) * DS_PITCH + d]);
#pragma unroll
      for (int li = 0; li < 4; ++li) {
        const float4 w = dv[li];
        acc[0][li] += qv[0].x * w.x + qv[1].x * w.y + qv[2].x * w.z + qv[3].x * w.w;
        acc[1][li] += qv[0].y * w.x + qv[1].y * w.y + qv[2].y * w.z + qv[3].y * w.w;
      }
    }
  }
  // all matmul READS of q_t/d_s must complete before m_s overlays q_t
  __syncthreads();
  if (tid < 64 * 14) {
    const int q0 = (tid & 63) << 1;
    const int l0 = (tid >> 6) << 2;
#pragma unroll
    for (int qi = 0; qi < 2; ++qi)
#pragma unroll
      for (int li = 0; li < 4; ++li)
        m_s[(q0 + qi) * MS_PITCH + (l0 + li)] = acc[qi][li];
  }
  __syncthreads();

  // ---- conv1(3x3)+bias+relu + top-8 row pool, split into 2 half-streams:
  // h=0: input rows 0..64 -> output idx 0..62; h=1: rows 63..127 -> 63..125.
  const int h    = tid & 1;
  const int pair = tid >> 1;          // (c,j): 0..407
  uint64_t key[8];
#pragma unroll
  for (int k = 0; k < 8; ++k) key[k] = 0;
  if (pair < kNPair) {
    const int c = pair / kTileC;
    const int j = pair % kTileC;
    float w[9];
#pragma unroll
    for (int k = 0; k < 9; ++k) w[k] = c1w[c * 9 + k];
    const float bias = c1b[c];
    const int tBase = h ? 63 : 0;

    float acc01 = 0.f, s0_pend = 0.f;
    for (int s = 0; s < 65; ++s) {
      const int t = tBase + s;
      const float x0 = m_s[t * MS_PITCH + j];
      const float x1 = m_s[t * MS_PITCH + j + 1];
      const float x2 = m_s[t * MS_PITCH + j + 2];
      const float S0 = w[0] * x0 + w[1] * x1 + w[2] * x2;
      const float S1 = w[3] * x0 + w[4] * x1 + w[5] * x2;
      const float S2 = w[6] * x0 + w[7] * x1 + w[8] * x2;
      if (s >= 2) {
        const float v = fmaxf(bias + acc01 + S2, 0.f);
        topk_u64<8>(key, pack_key(v, (unsigned)(t - 2)));
      }
      acc01 = s0_pend + S1;
      s0_pend = S0;
    }
    if (h == 1) {
#pragma unroll
      for (int k = 0; k < 8; ++k) hk[pair * 8 + k] = key[k];
    }
  }
  __syncthreads();

  // ---- h=0 threads merge partner list (exact: unique keys) + write ps ----
  if (pair < kNPair && h == 0) {
    const int c = pair / kTileC;
    const int j = pair % kTileC;
#pragma unroll
    for (int k = 0; k < 8; ++k) topk_u64<8>(key, hk[pair * 8 + k]);
    // slot = rank by idx asc = rank by low-word (~idx) desc
#pragma unroll
    for (int k = 0; k < 8; ++k) {
      const uint32_t lo_k = (uint32_t)key[k];
      int slot = 0;
#pragma unroll
      for (int m = 0; m < 8; ++m) slot += ((uint32_t)key[m] > lo_k);
      ps[(c * 8 + slot) * 52 + j] = __uint_as_float((uint32_t)(key[k] >> 32));
    }
  }
  __syncthreads();

  // ---- per-tile partial col-pool: top-8-of-51 per (c, slot-row) ----
  if (tid < 64) {
    const int g = tid;                 // g = c*8 + r
    uint64_t ck[8];
#pragma unroll
    for (int k = 0; k < 8; ++k) ck[k] = 0;
    for (int j = 0; j < kTileC; ++j)
      topk_u64<8>(ck, pack_key(ps[g * 52 + j], (unsigned)(l0g + j)));
    float* cv = candv + ((size_t)b * 64 + g) * kNCand + tile * 8;
    int*   ci = candi + ((size_t)b * 64 + g) * kNCand + tile * 8;
#pragma unroll
    for (int k = 0; k < 8; ++k) {
      const uint32_t lo_k = (uint32_t)ck[k];
      int slot = 0;
#pragma unroll
      for (int m = 0; m < 8; ++m) slot += ((uint32_t)ck[m] > lo_k);
      cv[slot] = __uint_as_float((uint32_t)(ck[k] >> 32));
      ci[slot] = (int)(~lo_k);
    }
  }
}

// =====================================================================
// Kernel B: per doc (512 thr): merge 80 candidates per (c,r) — hoisted
// loads + u64 chain + tournament -> [8][8][8]; conv2+relu -> [16][7][7];
// top-4 pools -> [16][4][4]; FC1 (4 thr/output + butterfly); FC2.
// =====================================================================
__global__ __launch_bounds__(512)
void tail_kernel(const float* __restrict__ candv, const int* __restrict__ candi,
                 const float* __restrict__ c2w, const float* __restrict__ c2b,
                 const float* __restrict__ l1w, const float* __restrict__ l1b,
                 const float* __restrict__ l2w, const float* __restrict__ l2b,
                 float* __restrict__ out) {
  __shared__ uint64_t mk[64][8][8];   // 32 KB tournament keys
  __shared__ float w2s[kC2 * kC1 * 4];
  __shared__ float b2s[kC2];
  __shared__ float h2in[kC1][8][8];
  __shared__ float h2o[kC2][7][7];
  __shared__ float h3[kC2][4][7];
  __shared__ __align__(16) float feat[256];
  __shared__ float zbuf[100];

  const int b = blockIdx.x, tid = threadIdx.x;

  if (tid < kC2 * kC1 * 4) w2s[tid] = c2w[tid];
  if (tid < kC2) b2s[tid] = c2b[tid];

  // ---- step 1: merge 80 candidates per (c,r), 8 lanes, loads hoisted ----
  const int g = tid >> 3, lane8 = tid & 7;   // g = c*8 + r
  uint64_t key[8];
#pragma unroll
  for (int k = 0; k < 8; ++k) key[k] = 0;
  {
    const float* cv = candv + ((size_t)b * 64 + g) * kNCand;
    const int*   ci = candi + ((size_t)b * 64 + g) * kNCand;
    float cvr[10]; int cir[10];
#pragma unroll
    for (int it = 0; it < 10; ++it) {
      cvr[it] = cv[lane8 + it * 8];
      cir[it] = ci[lane8 + it * 8];
    }
#pragma unroll
    for (int it = 0; it < 10; ++it)
      topk_u64<8>(key, pack_key(cvr[it], (unsigned)cir[it]));
#pragma unroll
    for (int k = 0; k < 8; ++k) mk[g][lane8][k] = key[k];
  }
  __syncthreads();

  // ---- tournament merge 8 -> 4 -> 2 -> 1 (u64: order-independent) ----
#pragma unroll
  for (int s = 4; s >= 1; s >>= 1) {
    if (lane8 < s) {
#pragma unroll
      for (int kk = 0; kk < 8; ++kk)
        topk_u64<8>(key, mk[g][lane8 + s][kk]);
      if (s > 1) {
#pragma unroll
        for (int k = 0; k < 8; ++k) mk[g][lane8][k] = key[k];
      }
    }
    __syncthreads();
  }
  if (lane8 == 0) {
    const int c = g >> 3, row = g & 7;
#pragma unroll
    for (int k = 0; k < 8; ++k) {
      const uint32_t lo_k = (uint32_t)key[k];
      int slot = 0;
#pragma unroll
      for (int m = 0; m < 8; ++m) slot += ((uint32_t)key[m] > lo_k);
      h2in[c][row][slot] = __uint_as_float((uint32_t)(key[k] >> 32));
    }
  }
  __syncthreads();

  // ---- step 2: conv2 2x2 (8->16) + relu ----
  for (int v = tid; v < kC2 * 49; v += 512) {
    const int c2 = v / 49;
    const int r  = (v % 49) / 7;
    const int j  = v % 7;
    float s = b2s[c2];
#pragma unroll
    for (int cin = 0; cin < kC1; ++cin) {
      const float* wp = &w2s[(c2 * kC1 + cin) * 4];
      s += wp[0] * h2in[cin][r][j]     + wp[1] * h2in[cin][r][j + 1];
      s += wp[2] * h2in[cin][r + 1][j] + wp[3] * h2in[cin][r + 1][j + 1];
    }
    h2o[c2][r][j] = fmaxf(s, 0.f);
  }
  __syncthreads();

  // ---- step 3: top-4-of-7 rows per (c2, j) ----
  if (tid < kC2 * 7) {
    const int c2 = tid / 7, j = tid % 7;
    uint64_t k4[4];
#pragma unroll
    for (int k = 0; k < 4; ++k) k4[k] = 0;
    for (int r = 0; r < 7; ++r) topk_u64<4>(k4, pack_key(h2o[c2][r][j], (unsigned)r));
#pragma unroll
    for (int k = 0; k < 4; ++k) {
      const uint32_t lo_k = (uint32_t)k4[k];
      int slot = 0;
#pragma unroll
      for (int m = 0; m < 4; ++m) slot += ((uint32_t)k4[m] > lo_k);
      h3[c2][slot][j] = __uint_as_float((uint32_t)(k4[k] >> 32));
    }
  }
  __syncthreads();

  // ---- step 4: top-4-of-7 cols per (c2, r) -> feat[256] ----
  if (tid < kC2 * 4) {
    const int c2 = tid >> 2, r = tid & 3;
    uint64_t k4[4];
#pragma unroll
    for (int k = 0; k < 4; ++k) k4[k] = 0;
    for (int j = 0; j < 7; ++j) topk_u64<4>(k4, pack_key(h3[c2][r][j], (unsigned)j));
#pragma unroll
    for (int k = 0; k < 4; ++k) {
      const uint32_t lo_k = (uint32_t)k4[k];
      int slot = 0;
#pragma unroll
      for (int m = 0; m < 4; ++m) slot += ((uint32_t)k4[m] > lo_k);
      feat[c2 * 16 + r * 4 + slot] = __uint_as_float((uint32_t)(k4[k] >> 32));
    }
  }
  __syncthreads();

  // ---- FC1: z = relu(feat @ W1^T + b1), 4 threads/output + butterfly ----
  if (tid < 400) {
    const int o = tid >> 2, part = tid & 3;
    const float4* wr = reinterpret_cast<const float4*>(l1w + (size_t)o * 256) + part * 16;
    const float4* fr = reinterpret_cast<const float4*>(feat) + part * 16;
    float s = 0.f;
#pragma unroll
    for (int i = 0; i < 16; ++i) {
      const float4 w = wr[i], f = fr[i];
      s += w.x * f.x + w.y * f.y + w.z * f.z + w.w * f.w;
    }
    s += __shfl_xor(s, 1, 64);   // quad-aligned partners, all active
    s += __shfl_xor(s, 2, 64);
    if (part == 0) zbuf[o] = fmaxf(s + l1b[o], 0.f);
  }
  __syncthreads();

  // ---- FC2: s = relu(z @ W2^T + b2), wave-0 reduce ----
  if (tid < 64) {
    float s = 0.f;
    for (int o = tid; o < 100; o += 64) s += zbuf[o] * l2w[o];
#pragma unroll
    for (int off = 32; off >= 1; off >>= 1) s += __shfl_down(s, off, 64);
    if (tid == 0) out[b] = fmaxf(s + l2b[0], 0.f);
  }
}

// =====================================================================
extern "C" void kernel_launch(void* const* d_in, const int* in_sizes, int n_in,
                              void* d_out, int out_size, void* d_ws,
                              size_t ws_size, hipStream_t stream) {
  const float* query    = (const float*)d_in[0];
  const float* pos_doc  = (const float*)d_in[1];
  const float* neg_docs = (const float*)d_in[2];
  const float* c1w      = (const float*)d_in[3];
  const float* c1b      = (const float*)d_in[4];
  const float* c2w      = (const float*)d_in[5];
  const float* c2b      = (const float*)d_in[6];
  const float* l1w      = (const float*)d_in[7];
  const float* l1b      = (const float*)d_in[8];
  const float* l2w      = (const float*)d_in[9];
  const float* l2b      = (const float*)d_in[10];
  float* out = (float*)d_out;

  // workspace: candv [128][8][8][80] f32, candi same in int (2.62 MB each)
  float* candv = (float*)d_ws;
  int*   candi = (int*)((char*)d_ws + (size_t)kB * 64 * kNCand * sizeof(float));

  dim3 gridA(kNTiles, kB);
  hipLaunchKernelGGL(convpool1_kernel, gridA, dim3(1024), 0, stream,
                     query, pos_doc, neg_docs, c1w, c1b, candv, candi);
  hipLaunchKernelGGL(tail_kernel, dim3(kB), dim3(512), 0, stream,
                     candv, candi, c2w, c2b, l1w, l1b, l2w, l2b, out);
}